// Round 1
// baseline (24880.817 us; speedup 1.0000x reference)
//
#include <hip/hip_runtime.h>
#include <math.h>

#define DMODEL 768
#define HN 12
#define DHEAD 64
#define DFF 3072
#define VOC 30522
#define BB 8
#define SS 128
#define KW 4
#define TT 32
#define CHN 239   // ceil(30522/128)
#define PG 256    // persistent grid size (1 block/CU guaranteed resident)
#define P32C (32 * DMODEL)

__device__ __forceinline__ float gelu_f(float x) {
    float x3 = x * x * x;
    return 0.5f * x * (1.0f + tanhf(0.7978845608028654f * (x + 0.044715f * x3)));
}

// ==================== encoder kernels (unchanged) ====================

__global__ __launch_bounds__(256) void embed_enc(const int* __restrict__ X,
                                                 const float* __restrict__ emb,
                                                 const float* __restrict__ pos,
                                                 float* __restrict__ h,
                                                 float* __restrict__ mb) {
    int row = blockIdx.x;
    int s = row & (SS - 1);
    int tok = X[row];
    const float* e = emb + (size_t)tok * DMODEL;
    const float* p = pos + (size_t)s * DMODEL;
    float* hp = h + (size_t)row * DMODEL;
    for (int c = threadIdx.x; c < DMODEL; c += 256) hp[c] = e[c] + p[c];
    if (threadIdx.x == 0) mb[row] = (tok != 0) ? 0.0f : -1e9f;
}

template<int KD, int ACT>
__global__ __launch_bounds__(256) void gemm64(const float* __restrict__ A,
                                              const float* __restrict__ B,
                                              float* __restrict__ C, int N) {
    __shared__ float As[16][68];
    __shared__ float Bs[16][68];
    int tid = threadIdx.x;
    int tx = tid & 15, ty = tid >> 4;
    int bm = blockIdx.y * 64, bn = blockIdx.x * 64;
    int a_gk = tid & 15, a_gm0 = tid >> 4;
    int b_gn = tid & 63, b_gk0 = tid >> 6;
    float ra[4], rb[4];
    float acc[4][4] = {};
#pragma unroll
    for (int p = 0; p < 4; p++) ra[p] = A[(size_t)(bm + a_gm0 + p * 16) * KD + a_gk];
#pragma unroll
    for (int p = 0; p < 4; p++) rb[p] = B[(size_t)(b_gk0 + p * 4) * N + bn + b_gn];
    for (int k0 = 0; k0 < KD; k0 += 16) {
        __syncthreads();
#pragma unroll
        for (int p = 0; p < 4; p++) As[a_gk][a_gm0 + p * 16] = ra[p];
#pragma unroll
        for (int p = 0; p < 4; p++) Bs[b_gk0 + p * 4][b_gn] = rb[p];
        __syncthreads();
        if (k0 + 16 < KD) {
#pragma unroll
            for (int p = 0; p < 4; p++) ra[p] = A[(size_t)(bm + a_gm0 + p * 16) * KD + k0 + 16 + a_gk];
#pragma unroll
            for (int p = 0; p < 4; p++) rb[p] = B[(size_t)(k0 + 16 + b_gk0 + p * 4) * N + bn + b_gn];
        }
#pragma unroll
        for (int kk = 0; kk < 16; kk++) {
            float4 a4 = *(const float4*)&As[kk][ty * 4];
            float4 b4 = *(const float4*)&Bs[kk][tx * 4];
            float av[4] = {a4.x, a4.y, a4.z, a4.w};
            float bv[4] = {b4.x, b4.y, b4.z, b4.w};
#pragma unroll
            for (int i = 0; i < 4; i++)
#pragma unroll
                for (int j = 0; j < 4; j++) acc[i][j] += av[i] * bv[j];
        }
    }
#pragma unroll
    for (int i = 0; i < 4; i++)
#pragma unroll
        for (int j = 0; j < 4; j++) {
            float v = acc[i][j];
            if (ACT) v = gelu_f(v);
            C[(size_t)(bm + ty * 4 + i) * N + bn + tx * 4 + j] = v;
        }
}

__global__ __launch_bounds__(64) void enc_attn(const float* __restrict__ q,
                                               const float* __restrict__ k,
                                               const float* __restrict__ v,
                                               const float* __restrict__ mb,
                                               float* __restrict__ ctx) {
    int bid = blockIdx.x;
    int qi = bid & (SS - 1);
    int h = (bid >> 7) % HN;
    int b = bid / (SS * HN);
    int lane = threadIdx.x;
    __shared__ float qs[DHEAD];
    __shared__ float att[SS];
    qs[lane] = q[((size_t)(b * SS + qi) * HN + h) * DHEAD + lane];
    __syncthreads();
    const float* kb = k + ((size_t)(b * SS) * HN + h) * DHEAD;
    const float* k0p = kb + (size_t)lane * DMODEL;
    const float* k1p = kb + (size_t)(lane + 64) * DMODEL;
    float s0 = 0.f, s1 = 0.f;
#pragma unroll 8
    for (int d = 0; d < DHEAD; d++) {
        float qd = qs[d];
        s0 += qd * k0p[d];
        s1 += qd * k1p[d];
    }
    s0 = s0 * 0.125f + mb[b * SS + lane];
    s1 = s1 * 0.125f + mb[b * SS + lane + 64];
    float m = fmaxf(s0, s1);
    for (int off = 32; off; off >>= 1) m = fmaxf(m, __shfl_xor(m, off, 64));
    float e0 = expf(s0 - m), e1 = expf(s1 - m);
    float sum = e0 + e1;
    for (int off = 32; off; off >>= 1) sum += __shfl_xor(sum, off, 64);
    float inv = 1.0f / sum;
    att[lane] = e0 * inv;
    att[lane + 64] = e1 * inv;
    __syncthreads();
    const float* vb = v + ((size_t)(b * SS) * HN + h) * DHEAD + lane;
    float acc = 0.f;
#pragma unroll 8
    for (int key = 0; key < SS; key++) acc += att[key] * vb[(size_t)key * DMODEL];
    ctx[(size_t)(b * SS + qi) * DMODEL + h * DHEAD + lane] = acc;
}

template<int P>
__global__ __launch_bounds__(256) void lnresP(const float* __restrict__ A,
                                              const float* __restrict__ Bsrc,
                                              float* __restrict__ out,
                                              float* __restrict__ outT,
                                              int wantT, int planeStride) {
    int row = blockIdx.x, tid = threadIdx.x;
    const float* ap = A + (size_t)row * DMODEL;
    float x[3];
#pragma unroll
    for (int i = 0; i < 3; i++) {
        int idx = tid + 256 * i;
        float s = ap[idx];
#pragma unroll
        for (int p = 0; p < P; p++) s += Bsrc[(size_t)p * planeStride + (size_t)row * DMODEL + idx];
        x[i] = s;
    }
    __shared__ float red[256];
    __shared__ float sm, sv;
    red[tid] = x[0] + x[1] + x[2];
    __syncthreads();
    for (int off = 128; off; off >>= 1) { if (tid < off) red[tid] += red[tid + off]; __syncthreads(); }
    if (tid == 0) sm = red[0] * (1.0f / DMODEL);
    __syncthreads();
    float mean = sm;
    float d[3], s2 = 0.f;
#pragma unroll
    for (int i = 0; i < 3; i++) { d[i] = x[i] - mean; s2 += d[i] * d[i]; }
    __syncthreads();
    red[tid] = s2;
    __syncthreads();
    for (int off = 128; off; off >>= 1) { if (tid < off) red[tid] += red[tid + off]; __syncthreads(); }
    if (tid == 0) sv = 1.0f / sqrtf(red[0] * (1.0f / DMODEL) + 1e-5f);
    __syncthreads();
    float inv = sv;
    float* op = out + (size_t)row * DMODEL;
#pragma unroll
    for (int i = 0; i < 3; i++) {
        float val = d[i] * inv;
        op[tid + 256 * i] = val;
        if (wantT) outT[(size_t)(tid + 256 * i) * 32 + row] = val;
    }
}

// ==================== persistent decode ====================

// sense-reversing grid barrier, device scope. bar[0]=counter, bar[1]=generation.
// Safe: 256 blocks x 256 thr always co-resident (>=1 block/CU at any VGPR<=512,
// LDS 25KB << 160KB). __syncthreads drains vmcnt before thread0 fences.
__device__ __forceinline__ void gsync(unsigned* bar) {
    __syncthreads();
    if (threadIdx.x == 0) {
        __threadfence();  // release: wb L2 so other XCDs see our block's stores
        unsigned g0 = __hip_atomic_load(bar + 1, __ATOMIC_RELAXED, __HIP_MEMORY_SCOPE_AGENT);
        unsigned a = __hip_atomic_fetch_add(bar, 1u, __ATOMIC_ACQ_REL, __HIP_MEMORY_SCOPE_AGENT);
        if (a == PG - 1) {
            __hip_atomic_store(bar, 0u, __ATOMIC_RELAXED, __HIP_MEMORY_SCOPE_AGENT);
            __hip_atomic_fetch_add(bar + 1, 1u, __ATOMIC_RELEASE, __HIP_MEMORY_SCOPE_AGENT);
        } else {
            while (__hip_atomic_load(bar + 1, __ATOMIC_RELAXED, __HIP_MEMORY_SCOPE_AGENT) == g0)
                __builtin_amdgcn_s_sleep(2);
        }
        __threadfence();  // acquire: inv L1/L2 so we see other XCDs' stores
    }
    __syncthreads();
}

__device__ __forceinline__ void embed_body(const int* __restrict__ tokens,
                                           const float* __restrict__ emb,
                                           const float* __restrict__ pos,
                                           int t, float* __restrict__ x,
                                           float* __restrict__ xT, int row) {
    int tok = tokens[row];
    const float* e = emb + (size_t)tok * DMODEL;
    const float* p = pos + (size_t)t * DMODEL;
    for (int c = threadIdx.x; c < DMODEL; c += 256) {
        float v = e[c] + p[c];
        x[(size_t)row * DMODEL + c] = v;
        xT[(size_t)c * 32 + row] = v;
    }
}

template<int KRANGE, int APL, int AGELU, int TOUT>
__device__ __forceinline__ void skinny3_body(float* Als,
                                             const float* __restrict__ At,
                                             const float* __restrict__ B,
                                             float* __restrict__ C,
                                             int N, int aPlaneF4, int bx, int by) {
    constexpr int SK = (KRANGE > 192) ? 192 : KRANGE;
    constexpr int NST = KRANGE / SK;
    int tid = threadIdx.x;
    int lane = tid & 63, q = tid >> 6;
    int col0 = bx * 128 + lane * 2;
    float acc[8][2] = {};
    for (int st = 0; st < NST; st++) {
        int kbase = by * KRANGE + st * SK;
        __syncthreads();
        const float4* srcb = ((const float4*)At) + (size_t)kbase * 8;
        float4* dst = (float4*)Als;
#pragma unroll
        for (int i = 0; i < SK / 32; i++) {
            float4 v = srcb[i * 256 + tid];
#pragma unroll
            for (int p = 1; p < APL; p++) {
                float4 w = srcb[(size_t)p * aPlaneF4 + i * 256 + tid];
                v.x += w.x; v.y += w.y; v.z += w.z; v.w += w.w;
            }
            if (AGELU) { v.x = gelu_f(v.x); v.y = gelu_f(v.y); v.z = gelu_f(v.z); v.w = gelu_f(v.w); }
            dst[i * 256 + tid] = v;
        }
        __syncthreads();
        const float* Bp = B + (size_t)kbase * N + col0;
#pragma unroll 8
        for (int k = 0; k < SK; k++) {
            float2 bv = *(const float2*)(Bp + (size_t)k * N);
            float4 a0 = *(const float4*)&Als[k * 32 + q * 8];
            float4 a1 = *(const float4*)&Als[k * 32 + q * 8 + 4];
            float ar[8] = {a0.x, a0.y, a0.z, a0.w, a1.x, a1.y, a1.z, a1.w};
#pragma unroll
            for (int r = 0; r < 8; r++) {
                acc[r][0] += ar[r] * bv.x;
                acc[r][1] += ar[r] * bv.y;
            }
        }
    }
    float* Cb = C + (size_t)by * 32 * N;
    if (TOUT) {
#pragma unroll
        for (int c = 0; c < 2; c++) {
            float4 lo = {acc[0][c], acc[1][c], acc[2][c], acc[3][c]};
            float4 hi = {acc[4][c], acc[5][c], acc[6][c], acc[7][c]};
            *(float4*)&Cb[(size_t)(col0 + c) * 32 + q * 8] = lo;
            *(float4*)&Cb[(size_t)(col0 + c) * 32 + q * 8 + 4] = hi;
        }
    } else {
#pragma unroll
        for (int r = 0; r < 8; r++) {
            float2 st2 = {acc[r][0], acc[r][1]};
            *(float2*)&Cb[(size_t)(q * 8 + r) * N + col0] = st2;
        }
    }
}

__device__ __forceinline__ void dec_attn_body(float* smem,
                                              const float* __restrict__ qdp,
                                              const float* __restrict__ Kmem,
                                              const float* __restrict__ Vmem,
                                              const float* __restrict__ mb,
                                              float* __restrict__ cctxT, int vb) {
    const int QP = 32 * DMODEL;
    int tid = threadIdx.x;
    int w = tid >> 6, lane = tid & 63;
    int unit = vb * 4 + w;          // == original blockIdx over 384
    int h = unit % HN;
    int kb = (unit / HN) & 3;
    int b = unit / (HN * KW);
    int rowq = b * KW + kb;
    float* qs = smem + w * 64;
    float* att = smem + 256 + w * SS;
    size_t qoff = (size_t)rowq * DMODEL + h * DHEAD + lane;
    float qv = 0.f;
#pragma unroll
    for (int p = 0; p < 8; p++) qv += qdp[(size_t)p * QP + qoff];
    qs[lane] = qv;
    __syncthreads();
    const float* kb0 = Kmem + ((size_t)(b * SS) * HN + h) * DHEAD;
    const float* k0p = kb0 + (size_t)lane * DMODEL;
    const float* k1p = kb0 + (size_t)(lane + 64) * DMODEL;
    float s0 = 0.f, s1 = 0.f;
#pragma unroll 8
    for (int d = 0; d < DHEAD; d++) {
        float qd = qs[d];
        s0 += qd * k0p[d];
        s1 += qd * k1p[d];
    }
    s0 = s0 * 0.125f + mb[b * SS + lane];
    s1 = s1 * 0.125f + mb[b * SS + lane + 64];
    float m = fmaxf(s0, s1);
    for (int off = 32; off; off >>= 1) m = fmaxf(m, __shfl_xor(m, off, 64));
    float e0 = expf(s0 - m), e1 = expf(s1 - m);
    float sum = e0 + e1;
    for (int off = 32; off; off >>= 1) sum += __shfl_xor(sum, off, 64);
    float inv = 1.0f / sum;
    att[lane] = e0 * inv;
    att[lane + 64] = e1 * inv;
    __syncthreads();
    const float* vb2 = Vmem + ((size_t)(b * SS) * HN + h) * DHEAD + lane;
    float acc = 0.f;
#pragma unroll 8
    for (int key = 0; key < SS; key++) acc += att[key] * vb2[(size_t)key * DMODEL];
    cctxT[(size_t)(h * DHEAD + lane) * 32 + rowq] = acc;
}

template<int P>
__device__ __forceinline__ void lnres_body(float* smem,
                                           const float* __restrict__ A,
                                           const float* __restrict__ Bsrc,
                                           float* __restrict__ out,
                                           float* __restrict__ outT,
                                           int planeStride, int row) {
    int tid = threadIdx.x;
    const float* ap = A + (size_t)row * DMODEL;
    float xx[3];
#pragma unroll
    for (int i = 0; i < 3; i++) {
        int idx = tid + 256 * i;
        float s = ap[idx];
#pragma unroll
        for (int p = 0; p < P; p++) s += Bsrc[(size_t)p * planeStride + (size_t)row * DMODEL + idx];
        xx[i] = s;
    }
    float* red = smem;
    red[tid] = xx[0] + xx[1] + xx[2];
    __syncthreads();
    for (int off = 128; off; off >>= 1) { if (tid < off) red[tid] += red[tid + off]; __syncthreads(); }
    if (tid == 0) smem[256] = red[0] * (1.0f / DMODEL);
    __syncthreads();
    float mean = smem[256];
    float d[3], s2 = 0.f;
#pragma unroll
    for (int i = 0; i < 3; i++) { d[i] = xx[i] - mean; s2 += d[i] * d[i]; }
    __syncthreads();
    red[tid] = s2;
    __syncthreads();
    for (int off = 128; off; off >>= 1) { if (tid < off) red[tid] += red[tid + off]; __syncthreads(); }
    if (tid == 0) smem[257] = 1.0f / sqrtf(red[0] * (1.0f / DMODEL) + 1e-5f);
    __syncthreads();
    float inv = smem[257];
    float* op = out + (size_t)row * DMODEL;
#pragma unroll
    for (int i = 0; i < 3; i++) {
        float val = d[i] * inv;
        op[tid + 256 * i] = val;
        outT[(size_t)(tid + 256 * i) * 32 + row] = val;
    }
}

__device__ __forceinline__ void logits_body(float* Als,
                                            const float* __restrict__ At,
                                            const float* __restrict__ B,
                                            float* __restrict__ cmax,
                                            float* __restrict__ csum,
                                            float* __restrict__ ctv,
                                            int* __restrict__ cti, int bx) {
    int tid = threadIdx.x;
    int lane = tid & 63, q = tid >> 6;
    int col0 = bx * 128 + lane * 2;
    bool valid = col0 < VOC;
    int jc = valid ? col0 : VOC - 2;
    float acc[8][2] = {};
    for (int st = 0; st < 4; st++) {
        int kbase = st * 192;
        __syncthreads();
        const float4* srcb = ((const float4*)At) + (size_t)kbase * 8;
        float4* dst = (float4*)Als;
#pragma unroll
        for (int i = 0; i < 6; i++) dst[i * 256 + tid] = srcb[i * 256 + tid];
        __syncthreads();
        const float* Bp = B + (size_t)kbase * VOC + jc;
#pragma unroll 16
        for (int k = 0; k < 192; k++) {
            float2 bv = *(const float2*)(Bp + (size_t)k * VOC);
            float4 a0 = *(const float4*)&Als[k * 32 + q * 8];
            float4 a1 = *(const float4*)&Als[k * 32 + q * 8 + 4];
            float ar[8] = {a0.x, a0.y, a0.z, a0.w, a1.x, a1.y, a1.z, a1.w};
#pragma unroll
            for (int r = 0; r < 8; r++) {
                acc[r][0] += ar[r] * bv.x;
                acc[r][1] += ar[r] * bv.y;
            }
        }
    }
#pragma unroll 1
    for (int r = 0; r < 8; r++) {
        float v0 = valid ? acc[r][0] : -INFINITY;
        float v1 = valid ? acc[r][1] : -INFINITY;
        float mx = fmaxf(v0, v1);
#pragma unroll
        for (int off = 32; off; off >>= 1) mx = fmaxf(mx, __shfl_xor(mx, off, 64));
        float ss = valid ? (expf(v0 - mx) + expf(v1 - mx)) : 0.0f;
#pragma unroll
        for (int off = 32; off; off >>= 1) ss += __shfl_xor(ss, off, 64);
        float c0 = v0, c1 = v1;
        int i0 = col0, i1 = col0 + 1;
        float tv[4]; int ti[4];
#pragma unroll
        for (int p = 0; p < 4; p++) {
            float bv; int bi;
            if (c0 > c1 || (c0 == c1 && i0 < i1)) { bv = c0; bi = i0; } else { bv = c1; bi = i1; }
#pragma unroll
            for (int off = 32; off; off >>= 1) {
                float ov = __shfl_xor(bv, off, 64);
                int oi = __shfl_xor(bi, off, 64);
                if (ov > bv || (ov == bv && oi < bi)) { bv = ov; bi = oi; }
            }
            if (bi == i0) c0 = -INFINITY;
            else if (bi == i1) c1 = -INFINITY;
            tv[p] = bv; ti[p] = bi;
        }
        if (lane == 0) {
            int m = q * 8 + r;
            int o = m * CHN + bx;
            cmax[o] = mx; csum[o] = ss;
            ctv[o * 4 + 0] = tv[0]; cti[o * 4 + 0] = ti[0];
            ctv[o * 4 + 1] = tv[1]; cti[o * 4 + 1] = ti[1];
            ctv[o * 4 + 2] = tv[2]; cti[o * 4 + 2] = ti[2];
            ctv[o * 4 + 3] = tv[3]; cti[o * 4 + 3] = ti[3];
        }
    }
}

__device__ __forceinline__ void merge_body(float* smem,
                                           const float* __restrict__ cmax,
                                           const float* __restrict__ csum,
                                           const float* __restrict__ ctv,
                                           const int* __restrict__ cti,
                                           float* __restrict__ scores,
                                           int* __restrict__ tokens,
                                           int* __restrict__ beamh,
                                           int* __restrict__ tokh, int t, int b) {
    int tid = threadIdx.x;
    int lane = tid & 63, q = tid >> 6;
    int m = b * 4 + q;
    float* s_old = smem;            // 4
    float* LSE = smem + 4;          // 4
    float* bt_v = smem + 8;         // 16
    int* bt_i = (int*)(smem + 24);  // 16
    if (tid < 4) s_old[tid] = scores[b * 4 + tid];
    float mx = -INFINITY, sm = 0.f;
    for (int c = lane; c < CHN; c += 64) {
        float cm = cmax[m * CHN + c], cs = csum[m * CHN + c];
        if (cm > mx) { sm = sm * expf(mx - cm) + cs; mx = cm; }
        else sm += cs * expf(cm - mx);
    }
#pragma unroll
    for (int off = 32; off; off >>= 1) {
        float om = __shfl_xor(mx, off, 64);
        float os = __shfl_xor(sm, off, 64);
        float M = fmaxf(mx, om);
        sm = sm * expf(mx - M) + os * expf(om - M);
        mx = M;
    }
    if (lane == 0) LSE[q] = mx + logf(sm);
    float lv[4] = {-INFINITY, -INFINITY, -INFINITY, -INFINITY};
    int li[4] = {0x7fffffff, 0x7fffffff, 0x7fffffff, 0x7fffffff};
    for (int c = lane; c < CHN; c += 64) {
        int o = (m * CHN + c) * 4;
#pragma unroll
        for (int j = 0; j < 4; j++) {
            float v = ctv[o + j]; int i = cti[o + j];
            if (v > lv[3] || (v == lv[3] && i < li[3])) {
                lv[3] = v; li[3] = i;
#pragma unroll
                for (int s = 3; s > 0; s--) {
                    if (lv[s] > lv[s - 1] || (lv[s] == lv[s - 1] && li[s] < li[s - 1])) {
                        float tv2 = lv[s]; lv[s] = lv[s - 1]; lv[s - 1] = tv2;
                        int ti2 = li[s]; li[s] = li[s - 1]; li[s - 1] = ti2;
                    }
                }
            }
        }
    }
#pragma unroll
    for (int p = 0; p < 4; p++) {
        float bv = lv[0]; int bi = li[0];
#pragma unroll
        for (int off = 32; off; off >>= 1) {
            float ov = __shfl_xor(bv, off, 64);
            int oi = __shfl_xor(bi, off, 64);
            if (ov > bv || (ov == bv && oi < bi)) { bv = ov; bi = oi; }
        }
        if (li[0] == bi) {
            lv[0] = lv[1]; li[0] = li[1];
            lv[1] = lv[2]; li[1] = li[2];
            lv[2] = lv[3]; li[2] = li[3];
            lv[3] = -INFINITY; li[3] = 0x7fffffff;
        }
        if (lane == 0) { bt_v[q * 4 + p] = bv; bt_i[q * 4 + p] = bi; }
    }
    __syncthreads();
    if (tid == 0) {
        float fv[16]; int fi[16]; bool used[16];
#pragma unroll
        for (int r = 0; r < 4; r++)
#pragma unroll
            for (int p = 0; p < 4; p++) {
                fv[r * 4 + p] = s_old[r] - LSE[r] + bt_v[r * 4 + p];
                fi[r * 4 + p] = r * VOC + bt_i[r * 4 + p];
                used[r * 4 + p] = false;
            }
        for (int kk = 0; kk < 4; kk++) {
            int best = -1;
            for (int c2 = 0; c2 < 16; c2++) {
                if (used[c2]) continue;
                if (best < 0 || fv[c2] > fv[best] || (fv[c2] == fv[best] && fi[c2] < fi[best])) best = c2;
            }
            used[best] = true;
            int beam = fi[best] / VOC;
            int tok = fi[best] - beam * VOC;
            scores[b * 4 + kk] = fv[best];
            tokens[b * 4 + kk] = tok;
            beamh[(t * BB + b) * 4 + kk] = beam;
            tokh[(t * BB + b) * 4 + kk] = tok;
        }
    }
}

__global__ __launch_bounds__(256) void decode_persistent(
    const float* __restrict__ emb, const float* __restrict__ pos,
    const float* __restrict__ Wdq, const float* __restrict__ Wdo,
    const float* __restrict__ Wd1, const float* __restrict__ Wd2,
    const float* __restrict__ Wvoc,
    const float* __restrict__ Kmem, const float* __restrict__ Vmem,
    const float* __restrict__ mb,
    float* __restrict__ x, float* __restrict__ xT,
    float* __restrict__ qdp, float* __restrict__ cctxT, float* __restrict__ cprojp,
    float* __restrict__ hd1, float* __restrict__ hd1T,
    float* __restrict__ dff1p, float* __restrict__ dff2p,
    float* __restrict__ hd2, float* __restrict__ hd2T,
    float* __restrict__ cmax, float* __restrict__ csum,
    float* __restrict__ ctv, int* __restrict__ cti,
    float* __restrict__ scores, int* __restrict__ tokens,
    int* __restrict__ beamh, int* __restrict__ tokh,
    unsigned* bar, float* __restrict__ out) {
    __shared__ float smem[6160];   // 24.6 KB: max(logits/skinny staging 6144, attn 768, ln 258)
    int bid = blockIdx.x, tid = threadIdx.x;

    // init tokens/scores
    if (bid == 0 && tid < BB * KW) {
        tokens[tid] = 101;
        scores[tid] = (tid & 3) ? -1e9f : 0.0f;
    }
    gsync(bar);

    for (int t = 0; t < TT; t++) {
        if (bid < 32) embed_body(tokens, emb, pos, t, x, xT, bid);
        gsync(bar);
        if (bid < 48) skinny3_body<96, 1, 0, 0>(smem, xT, Wdq, qdp, DMODEL, 0, bid % 6, bid / 6);
        gsync(bar);
        if (bid < 96) dec_attn_body(smem, qdp, Kmem, Vmem, mb, cctxT, bid);
        gsync(bar);
        if (bid < 48) skinny3_body<96, 1, 0, 0>(smem, cctxT, Wdo, cprojp, DMODEL, 0, bid % 6, bid / 6);
        gsync(bar);
        if (bid < 32) lnres_body<8>(smem, x, cprojp, hd1, hd1T, P32C, bid);
        gsync(bar);
        if (bid < 96) skinny3_body<192, 1, 0, 1>(smem, hd1T, Wd1, dff1p, DFF, 0, bid % 24, bid / 24);
        gsync(bar);
        if (bid < 48) skinny3_body<384, 4, 1, 0>(smem, dff1p, Wd2, dff2p, DMODEL, DFF * 8, bid % 6, bid / 6);
        gsync(bar);
        if (bid < 32) lnres_body<8>(smem, hd1, dff2p, hd2, hd2T, P32C, bid);
        gsync(bar);
        if (bid < CHN) logits_body(smem, hd2T, Wvoc, cmax, csum, ctv, cti, bid);
        gsync(bar);
        if (bid < BB) merge_body(smem, cmax, csum, ctv, cti, scores, tokens, beamh, tokh, t, bid);
        gsync(bar);
    }

    // backtrack
    if (bid == 0 && tid < BB * KW) {
        int b = tid >> 2, k = tid & 3;
        int ptr = k;
        for (int t = TT - 1; t >= 0; t--) {
            int tok = tokh[(t * BB + b) * KW + ptr];
            out[(size_t)tid * TT + t] = (float)tok;
            ptr = beamh[(t * BB + b) * KW + ptr];
        }
        out[BB * KW * TT + tid] = scores[tid];
    }
}

__global__ void init_k(unsigned* bar) {
    if (threadIdx.x < 2) bar[threadIdx.x] = 0u;
}

extern "C" void kernel_launch(void* const* d_in, const int* in_sizes, int n_in,
                              void* d_out, int out_size, void* d_ws, size_t ws_size,
                              hipStream_t stream) {
    const int* X = (const int*)d_in[0];
    const float* emb = (const float*)d_in[1];
    const float* pos = (const float*)d_in[2];
    const float* Wq = (const float*)d_in[3];
    const float* Wk = (const float*)d_in[4];
    const float* Wv = (const float*)d_in[5];
    const float* Wo = (const float*)d_in[6];
    const float* W1 = (const float*)d_in[7];
    const float* W2 = (const float*)d_in[8];
    const float* Wdq = (const float*)d_in[9];
    const float* Wdk = (const float*)d_in[10];
    const float* Wdv = (const float*)d_in[11];
    const float* Wdo = (const float*)d_in[12];
    const float* Wd1 = (const float*)d_in[13];
    const float* Wd2 = (const float*)d_in[14];
    const float* Wvoc = (const float*)d_in[15];

    float* ws = (float*)d_ws;
    size_t o = 0;
    auto alloc = [&](size_t n) { float* p = ws + o; o += n; return p; };

    const size_t ROWS = (size_t)BB * SS;       // 1024
    const size_t HD = ROWS * DMODEL;
    const size_t P32 = 32 * DMODEL;            // 24576

    // persistent
    float* mb = alloc(ROWS);
    float* Kmem = alloc(HD);
    float* Vmem = alloc(HD);
    float* scores = alloc(32);
    int* tokens = (int*)alloc(32);
    int* beamh = (int*)alloc(TT * BB * KW);
    int* tokh = (int*)alloc(TT * BB * KW);
    unsigned* bar = (unsigned*)alloc(2);

    size_t mark = o;
    // encoder scratch
    float* h0 = alloc(HD);
    float* qb = alloc(HD);
    float* kb = alloc(HD);
    float* vb = alloc(HD);
    float* attc = alloc(HD);
    float* attp = alloc(HD);
    float* h1 = alloc(HD);
    float* ff1 = alloc(ROWS * DFF);
    float* ff2 = alloc(HD);
    float* memb = alloc(HD);

    // decoder scratch (aliases encoder scratch)
    o = mark;
    float* x = alloc(P32);
    float* xT = alloc(P32);
    float* qdp = alloc(8 * P32);
    float* cctxT = alloc(P32);
    float* cprojp = alloc(8 * P32);
    float* hd1 = alloc(P32);
    float* hd1T = alloc(P32);
    float* dff1p = alloc((size_t)4 * DFF * 32);
    float* dff2p = alloc(8 * P32);
    float* hd2 = alloc(P32);
    float* hd2T = alloc(P32);
    float* cmax = alloc(32 * CHN);
    float* csum = alloc(32 * CHN);
    float* ctv = alloc((size_t)32 * CHN * 4);
    int* cti = (int*)alloc((size_t)32 * CHN * 4);
    (void)ws_size; (void)in_sizes; (void)n_in; (void)out_size;

    init_k<<<1, 64, 0, stream>>>(bar);

    // ---- encoder (unchanged) ----
    embed_enc<<<dim3(ROWS), 256, 0, stream>>>(X, emb, pos, h0, mb);
    dim3 g768(DMODEL / 64, ROWS / 64);
    dim3 g3072(DFF / 64, ROWS / 64);
    gemm64<DMODEL, 0><<<g768, 256, 0, stream>>>(h0, Wq, qb, DMODEL);
    gemm64<DMODEL, 0><<<g768, 256, 0, stream>>>(h0, Wk, kb, DMODEL);
    gemm64<DMODEL, 0><<<g768, 256, 0, stream>>>(h0, Wv, vb, DMODEL);
    enc_attn<<<dim3(BB * HN * SS), 64, 0, stream>>>(qb, kb, vb, mb, attc);
    gemm64<DMODEL, 0><<<g768, 256, 0, stream>>>(attc, Wo, attp, DMODEL);
    lnresP<1><<<dim3(ROWS), 256, 0, stream>>>(h0, attp, h1, nullptr, 0, 0);
    gemm64<DMODEL, 1><<<g3072, 256, 0, stream>>>(h1, W1, ff1, DFF);
    gemm64<DFF, 0><<<g768, 256, 0, stream>>>(ff1, W2, ff2, DMODEL);
    lnresP<1><<<dim3(ROWS), 256, 0, stream>>>(h1, ff2, memb, nullptr, 0, 0);
    gemm64<DMODEL, 0><<<g768, 256, 0, stream>>>(memb, Wdk, Kmem, DMODEL);
    gemm64<DMODEL, 0><<<g768, 256, 0, stream>>>(memb, Wdv, Vmem, DMODEL);

    // ---- entire beam-search decode in ONE persistent kernel ----
    decode_persistent<<<dim3(PG), 256, 0, stream>>>(
        emb, pos, Wdq, Wdo, Wd1, Wd2, Wvoc, Kmem, Vmem, mb,
        x, xT, qdp, cctxT, cprojp, hd1, hd1T, dff1p, dff2p, hd2, hd2T,
        cmax, csum, ctv, cti, scores, tokens, beamh, tokh, bar, (float*)d_out);
}

// Round 2
// 19100.067 us; speedup vs baseline: 1.3027x; 1.3027x over previous
//
#include <hip/hip_runtime.h>
#include <math.h>

#define DMODEL 768
#define HN 12
#define DHEAD 64
#define DFF 3072
#define VOC 30522
#define BB 8
#define SS 128
#define KW 4
#define TT 32
#define CHN 239   // ceil(30522/128)
#define PG 256    // persistent grid size
#define P32C (32 * DMODEL)
#define SLOT 16   // barrier slot stride (64B) to spread MALL banks

__device__ __forceinline__ float gelu_f(float x) {
    float x3 = x * x * x;
    return 0.5f * x * (1.0f + tanhf(0.7978845608028654f * (x + 0.044715f * x3)));
}

// ---------- coherent (MALL-level, L1/L2-bypassing) scratch access ----------
__device__ __forceinline__ float cld(const float* p) {
    return __hip_atomic_load(p, __ATOMIC_RELAXED, __HIP_MEMORY_SCOPE_AGENT);
}
__device__ __forceinline__ void cst(float* p, float v) {
    __hip_atomic_store(p, v, __ATOMIC_RELAXED, __HIP_MEMORY_SCOPE_AGENT);
}
__device__ __forceinline__ int cldi(const int* p) {
    return __hip_atomic_load(p, __ATOMIC_RELAXED, __HIP_MEMORY_SCOPE_AGENT);
}
__device__ __forceinline__ void csti(int* p, int v) {
    __hip_atomic_store(p, v, __ATOMIC_RELAXED, __HIP_MEMORY_SCOPE_AGENT);
}
__device__ __forceinline__ float2 cld2(const float* p) {
    unsigned long long u = __hip_atomic_load((const unsigned long long*)p,
                                             __ATOMIC_RELAXED, __HIP_MEMORY_SCOPE_AGENT);
    float2 r; __builtin_memcpy(&r, &u, 8); return r;
}
__device__ __forceinline__ void cst2(float* p, float a, float b) {
    float2 v = make_float2(a, b);
    unsigned long long u; __builtin_memcpy(&u, &v, 8);
    __hip_atomic_store((unsigned long long*)p, u, __ATOMIC_RELAXED, __HIP_MEMORY_SCOPE_AGENT);
}
__device__ __forceinline__ float4 cld4(const float* p) {
    float2 a = cld2(p), b = cld2(p + 2);
    return make_float4(a.x, a.y, b.x, b.y);
}
__device__ __forceinline__ void cst4(float* p, float4 v) {
    cst2(p, v.x, v.y); cst2(p + 2, v.z, v.w);
}

// ==================== encoder kernels (unchanged) ====================

__global__ __launch_bounds__(256) void embed_enc(const int* __restrict__ X,
                                                 const float* __restrict__ emb,
                                                 const float* __restrict__ pos,
                                                 float* __restrict__ h,
                                                 float* __restrict__ mb) {
    int row = blockIdx.x;
    int s = row & (SS - 1);
    int tok = X[row];
    const float* e = emb + (size_t)tok * DMODEL;
    const float* p = pos + (size_t)s * DMODEL;
    float* hp = h + (size_t)row * DMODEL;
    for (int c = threadIdx.x; c < DMODEL; c += 256) hp[c] = e[c] + p[c];
    if (threadIdx.x == 0) mb[row] = (tok != 0) ? 0.0f : -1e9f;
}

template<int KD, int ACT>
__global__ __launch_bounds__(256) void gemm64(const float* __restrict__ A,
                                              const float* __restrict__ B,
                                              float* __restrict__ C, int N) {
    __shared__ float As[16][68];
    __shared__ float Bs[16][68];
    int tid = threadIdx.x;
    int tx = tid & 15, ty = tid >> 4;
    int bm = blockIdx.y * 64, bn = blockIdx.x * 64;
    int a_gk = tid & 15, a_gm0 = tid >> 4;
    int b_gn = tid & 63, b_gk0 = tid >> 6;
    float ra[4], rb[4];
    float acc[4][4] = {};
#pragma unroll
    for (int p = 0; p < 4; p++) ra[p] = A[(size_t)(bm + a_gm0 + p * 16) * KD + a_gk];
#pragma unroll
    for (int p = 0; p < 4; p++) rb[p] = B[(size_t)(b_gk0 + p * 4) * N + bn + b_gn];
    for (int k0 = 0; k0 < KD; k0 += 16) {
        __syncthreads();
#pragma unroll
        for (int p = 0; p < 4; p++) As[a_gk][a_gm0 + p * 16] = ra[p];
#pragma unroll
        for (int p = 0; p < 4; p++) Bs[b_gk0 + p * 4][b_gn] = rb[p];
        __syncthreads();
        if (k0 + 16 < KD) {
#pragma unroll
            for (int p = 0; p < 4; p++) ra[p] = A[(size_t)(bm + a_gm0 + p * 16) * KD + k0 + 16 + a_gk];
#pragma unroll
            for (int p = 0; p < 4; p++) rb[p] = B[(size_t)(k0 + 16 + b_gk0 + p * 4) * N + bn + b_gn];
        }
#pragma unroll
        for (int kk = 0; kk < 16; kk++) {
            float4 a4 = *(const float4*)&As[kk][ty * 4];
            float4 b4 = *(const float4*)&Bs[kk][tx * 4];
            float av[4] = {a4.x, a4.y, a4.z, a4.w};
            float bv[4] = {b4.x, b4.y, b4.z, b4.w};
#pragma unroll
            for (int i = 0; i < 4; i++)
#pragma unroll
                for (int j = 0; j < 4; j++) acc[i][j] += av[i] * bv[j];
        }
    }
#pragma unroll
    for (int i = 0; i < 4; i++)
#pragma unroll
        for (int j = 0; j < 4; j++) {
            float v = acc[i][j];
            if (ACT) v = gelu_f(v);
            C[(size_t)(bm + ty * 4 + i) * N + bn + tx * 4 + j] = v;
        }
}

__global__ __launch_bounds__(64) void enc_attn(const float* __restrict__ q,
                                               const float* __restrict__ k,
                                               const float* __restrict__ v,
                                               const float* __restrict__ mb,
                                               float* __restrict__ ctx) {
    int bid = blockIdx.x;
    int qi = bid & (SS - 1);
    int h = (bid >> 7) % HN;
    int b = bid / (SS * HN);
    int lane = threadIdx.x;
    __shared__ float qs[DHEAD];
    __shared__ float att[SS];
    qs[lane] = q[((size_t)(b * SS + qi) * HN + h) * DHEAD + lane];
    __syncthreads();
    const float* kb = k + ((size_t)(b * SS) * HN + h) * DHEAD;
    const float* k0p = kb + (size_t)lane * DMODEL;
    const float* k1p = kb + (size_t)(lane + 64) * DMODEL;
    float s0 = 0.f, s1 = 0.f;
#pragma unroll 8
    for (int d = 0; d < DHEAD; d++) {
        float qd = qs[d];
        s0 += qd * k0p[d];
        s1 += qd * k1p[d];
    }
    s0 = s0 * 0.125f + mb[b * SS + lane];
    s1 = s1 * 0.125f + mb[b * SS + lane + 64];
    float m = fmaxf(s0, s1);
    for (int off = 32; off; off >>= 1) m = fmaxf(m, __shfl_xor(m, off, 64));
    float e0 = expf(s0 - m), e1 = expf(s1 - m);
    float sum = e0 + e1;
    for (int off = 32; off; off >>= 1) sum += __shfl_xor(sum, off, 64);
    float inv = 1.0f / sum;
    att[lane] = e0 * inv;
    att[lane + 64] = e1 * inv;
    __syncthreads();
    const float* vb = v + ((size_t)(b * SS) * HN + h) * DHEAD + lane;
    float acc = 0.f;
#pragma unroll 8
    for (int key = 0; key < SS; key++) acc += att[key] * vb[(size_t)key * DMODEL];
    ctx[(size_t)(b * SS + qi) * DMODEL + h * DHEAD + lane] = acc;
}

template<int P>
__global__ __launch_bounds__(256) void lnresP(const float* __restrict__ A,
                                              const float* __restrict__ Bsrc,
                                              float* __restrict__ out,
                                              float* __restrict__ outT,
                                              int wantT, int planeStride) {
    int row = blockIdx.x, tid = threadIdx.x;
    const float* ap = A + (size_t)row * DMODEL;
    float x[3];
#pragma unroll
    for (int i = 0; i < 3; i++) {
        int idx = tid + 256 * i;
        float s = ap[idx];
#pragma unroll
        for (int p = 0; p < P; p++) s += Bsrc[(size_t)p * planeStride + (size_t)row * DMODEL + idx];
        x[i] = s;
    }
    __shared__ float red[256];
    __shared__ float sm, sv;
    red[tid] = x[0] + x[1] + x[2];
    __syncthreads();
    for (int off = 128; off; off >>= 1) { if (tid < off) red[tid] += red[tid + off]; __syncthreads(); }
    if (tid == 0) sm = red[0] * (1.0f / DMODEL);
    __syncthreads();
    float mean = sm;
    float d[3], s2 = 0.f;
#pragma unroll
    for (int i = 0; i < 3; i++) { d[i] = x[i] - mean; s2 += d[i] * d[i]; }
    __syncthreads();
    red[tid] = s2;
    __syncthreads();
    for (int off = 128; off; off >>= 1) { if (tid < off) red[tid] += red[tid + off]; __syncthreads(); }
    if (tid == 0) sv = 1.0f / sqrtf(red[0] * (1.0f / DMODEL) + 1e-5f);
    __syncthreads();
    float inv = sv;
    float* op = out + (size_t)row * DMODEL;
#pragma unroll
    for (int i = 0; i < 3; i++) {
        float val = d[i] * inv;
        op[tid + 256 * i] = val;
        if (wantT) outT[(size_t)(tid + 256 * i) * 32 + row] = val;
    }
}

// ==================== persistent decode ====================

// Distributed two-hop grid barrier: no shared hot line, no cache-flush fences.
// Every block stores its arrival generation into its own padded slot (agent
// scope -> coherence point). Block 0's threads poll one slot each, then fan
// out per-block release slots. Generations are monotonic (no reset race).
// Data coherence: ALL inter-phase scratch uses agent-scope relaxed atomics
// (cld/cst), which bypass per-XCD L2 -> no stale copies, no wbl2/inv needed.
__device__ __forceinline__ void gsync(unsigned* abar, unsigned* rbar, unsigned& gen) {
    gen++;
    int bid = blockIdx.x, tid = threadIdx.x;
    __syncthreads();   // drains vmcnt(0): all this block's scratch stores are at the coherence point
    asm volatile("s_waitcnt vmcnt(0)" ::: "memory");
    if (bid == 0) {
        if (tid > 0) {   // thread tid waits for block tid's arrival
            while (__hip_atomic_load(abar + tid * SLOT, __ATOMIC_RELAXED, __HIP_MEMORY_SCOPE_AGENT) < gen)
                __builtin_amdgcn_s_sleep(1);
        }
        __syncthreads(); // all arrivals observed before any release
        if (tid > 0)
            __hip_atomic_store(rbar + tid * SLOT, gen, __ATOMIC_RELAXED, __HIP_MEMORY_SCOPE_AGENT);
    } else {
        if (tid == 0) {
            __hip_atomic_store(abar + bid * SLOT, gen, __ATOMIC_RELAXED, __HIP_MEMORY_SCOPE_AGENT);
            while (__hip_atomic_load(rbar + bid * SLOT, __ATOMIC_RELAXED, __HIP_MEMORY_SCOPE_AGENT) < gen)
                __builtin_amdgcn_s_sleep(1);
        }
    }
    __syncthreads();
}

__device__ __forceinline__ void embed_body(float* smem,
                                           const int* __restrict__ tokens,
                                           const float* __restrict__ emb,
                                           const float* __restrict__ pos,
                                           int t, float* __restrict__ x,
                                           float* __restrict__ xT, int row) {
    if (threadIdx.x == 0) ((int*)smem)[0] = cldi(tokens + row);
    __syncthreads();
    int tok = ((int*)smem)[0];
    const float* e = emb + (size_t)tok * DMODEL;
    const float* p = pos + (size_t)t * DMODEL;
    for (int c = threadIdx.x; c < DMODEL; c += 256) {
        float v = e[c] + p[c];
        cst(x + (size_t)row * DMODEL + c, v);
        cst(xT + (size_t)c * 32 + row, v);
    }
}

template<int KRANGE, int APL, int AGELU, int TOUT>
__device__ __forceinline__ void skinny3_body(float* Als,
                                             const float* __restrict__ At,
                                             const float* __restrict__ B,
                                             float* __restrict__ C,
                                             int N, int aPlaneF4, int bx, int by) {
    constexpr int SK = (KRANGE > 192) ? 192 : KRANGE;
    constexpr int NST = KRANGE / SK;
    int tid = threadIdx.x;
    int lane = tid & 63, q = tid >> 6;
    int col0 = bx * 128 + lane * 2;
    float acc[8][2] = {};
    for (int st = 0; st < NST; st++) {
        int kbase = by * KRANGE + st * SK;
        __syncthreads();
        const float* srcb = At + (size_t)kbase * 32;
        float4* dst = (float4*)Als;
#pragma unroll
        for (int i = 0; i < SK / 32; i++) {
            float4 v = cld4(srcb + (size_t)(i * 256 + tid) * 4);
#pragma unroll
            for (int p = 1; p < APL; p++) {
                float4 w = cld4(srcb + ((size_t)p * aPlaneF4 + i * 256 + tid) * 4);
                v.x += w.x; v.y += w.y; v.z += w.z; v.w += w.w;
            }
            if (AGELU) { v.x = gelu_f(v.x); v.y = gelu_f(v.y); v.z = gelu_f(v.z); v.w = gelu_f(v.w); }
            dst[i * 256 + tid] = v;
        }
        __syncthreads();
        const float* Bp = B + (size_t)kbase * N + col0;
#pragma unroll 8
        for (int k = 0; k < SK; k++) {
            float2 bv = *(const float2*)(Bp + (size_t)k * N);
            float4 a0 = *(const float4*)&Als[k * 32 + q * 8];
            float4 a1 = *(const float4*)&Als[k * 32 + q * 8 + 4];
            float ar[8] = {a0.x, a0.y, a0.z, a0.w, a1.x, a1.y, a1.z, a1.w};
#pragma unroll
            for (int r = 0; r < 8; r++) {
                acc[r][0] += ar[r] * bv.x;
                acc[r][1] += ar[r] * bv.y;
            }
        }
    }
    float* Cb = C + (size_t)by * 32 * N;
    if (TOUT) {
#pragma unroll
        for (int c = 0; c < 2; c++) {
            float4 lo = {acc[0][c], acc[1][c], acc[2][c], acc[3][c]};
            float4 hi = {acc[4][c], acc[5][c], acc[6][c], acc[7][c]};
            cst4(&Cb[(size_t)(col0 + c) * 32 + q * 8], lo);
            cst4(&Cb[(size_t)(col0 + c) * 32 + q * 8 + 4], hi);
        }
    } else {
#pragma unroll
        for (int r = 0; r < 8; r++)
            cst2(&Cb[(size_t)(q * 8 + r) * N + col0], acc[r][0], acc[r][1]);
    }
}

__device__ __forceinline__ void dec_attn_body(float* smem,
                                              const float* __restrict__ qdp,
                                              const float* __restrict__ Kmem,
                                              const float* __restrict__ Vmem,
                                              const float* __restrict__ mb,
                                              float* __restrict__ cctxT, int vb) {
    const int QP = 32 * DMODEL;
    int tid = threadIdx.x;
    int w = tid >> 6, lane = tid & 63;
    int unit = vb * 4 + w;
    int h = unit % HN;
    int kb = (unit / HN) & 3;
    int b = unit / (HN * KW);
    int rowq = b * KW + kb;
    float* qs = smem + w * 64;
    float* att = smem + 256 + w * SS;
    size_t qoff = (size_t)rowq * DMODEL + h * DHEAD + lane;
    float qv = 0.f;
#pragma unroll
    for (int p = 0; p < 8; p++) qv += cld(qdp + (size_t)p * QP + qoff);
    qs[lane] = qv;
    __syncthreads();
    const float* kb0 = Kmem + ((size_t)(b * SS) * HN + h) * DHEAD;
    const float* k0p = kb0 + (size_t)lane * DMODEL;
    const float* k1p = kb0 + (size_t)(lane + 64) * DMODEL;
    float s0 = 0.f, s1 = 0.f;
#pragma unroll 8
    for (int d = 0; d < DHEAD; d++) {
        float qd = qs[d];
        s0 += qd * k0p[d];
        s1 += qd * k1p[d];
    }
    s0 = s0 * 0.125f + mb[b * SS + lane];
    s1 = s1 * 0.125f + mb[b * SS + lane + 64];
    float m = fmaxf(s0, s1);
    for (int off = 32; off; off >>= 1) m = fmaxf(m, __shfl_xor(m, off, 64));
    float e0 = expf(s0 - m), e1 = expf(s1 - m);
    float sum = e0 + e1;
    for (int off = 32; off; off >>= 1) sum += __shfl_xor(sum, off, 64);
    float inv = 1.0f / sum;
    att[lane] = e0 * inv;
    att[lane + 64] = e1 * inv;
    __syncthreads();
    const float* vb2 = Vmem + ((size_t)(b * SS) * HN + h) * DHEAD + lane;
    float acc = 0.f;
#pragma unroll 8
    for (int key = 0; key < SS; key++) acc += att[key] * vb2[(size_t)key * DMODEL];
    cst(cctxT + (size_t)(h * DHEAD + lane) * 32 + rowq, acc);
}

template<int P>
__device__ __forceinline__ void lnres_body(float* smem,
                                           const float* __restrict__ A,
                                           const float* __restrict__ Bsrc,
                                           float* __restrict__ out,
                                           float* __restrict__ outT,
                                           int planeStride, int row) {
    int tid = threadIdx.x;
    const float* ap = A + (size_t)row * DMODEL;
    float xx[3];
#pragma unroll
    for (int i = 0; i < 3; i++) {
        int idx = tid + 256 * i;
        float s = cld(ap + idx);
#pragma unroll
        for (int p = 0; p < P; p++) s += cld(Bsrc + (size_t)p * planeStride + (size_t)row * DMODEL + idx);
        xx[i] = s;
    }
    float* red = smem;
    red[tid] = xx[0] + xx[1] + xx[2];
    __syncthreads();
    for (int off = 128; off; off >>= 1) { if (tid < off) red[tid] += red[tid + off]; __syncthreads(); }
    if (tid == 0) smem[256] = red[0] * (1.0f / DMODEL);
    __syncthreads();
    float mean = smem[256];
    float d[3], s2 = 0.f;
#pragma unroll
    for (int i = 0; i < 3; i++) { d[i] = xx[i] - mean; s2 += d[i] * d[i]; }
    __syncthreads();
    red[tid] = s2;
    __syncthreads();
    for (int off = 128; off; off >>= 1) { if (tid < off) red[tid] += red[tid + off]; __syncthreads(); }
    if (tid == 0) smem[257] = 1.0f / sqrtf(red[0] * (1.0f / DMODEL) + 1e-5f);
    __syncthreads();
    float inv = smem[257];
    float* op = out + (size_t)row * DMODEL;
#pragma unroll
    for (int i = 0; i < 3; i++) {
        float val = d[i] * inv;
        cst(op + tid + 256 * i, val);
        cst(outT + (size_t)(tid + 256 * i) * 32 + row, val);
    }
}

__device__ __forceinline__ void logits_body(float* Als,
                                            const float* __restrict__ At,
                                            const float* __restrict__ B,
                                            float* __restrict__ cmax,
                                            float* __restrict__ csum,
                                            float* __restrict__ ctv,
                                            int* __restrict__ cti, int bx) {
    int tid = threadIdx.x;
    int lane = tid & 63, q = tid >> 6;
    int col0 = bx * 128 + lane * 2;
    bool valid = col0 < VOC;
    int jc = valid ? col0 : VOC - 2;
    float acc[8][2] = {};
    for (int st = 0; st < 4; st++) {
        int kbase = st * 192;
        __syncthreads();
        const float* srcb = At + (size_t)kbase * 32;
        float4* dst = (float4*)Als;
#pragma unroll
        for (int i = 0; i < 6; i++) dst[i * 256 + tid] = cld4(srcb + (size_t)(i * 256 + tid) * 4);
        __syncthreads();
        const float* Bp = B + (size_t)kbase * VOC + jc;
#pragma unroll 16
        for (int k = 0; k < 192; k++) {
            float2 bv = *(const float2*)(Bp + (size_t)k * VOC);
            float4 a0 = *(const float4*)&Als[k * 32 + q * 8];
            float4 a1 = *(const float4*)&Als[k * 32 + q * 8 + 4];
            float ar[8] = {a0.x, a0.y, a0.z, a0.w, a1.x, a1.y, a1.z, a1.w};
#pragma unroll
            for (int r = 0; r < 8; r++) {
                acc[r][0] += ar[r] * bv.x;
                acc[r][1] += ar[r] * bv.y;
            }
        }
    }
#pragma unroll 1
    for (int r = 0; r < 8; r++) {
        float v0 = valid ? acc[r][0] : -INFINITY;
        float v1 = valid ? acc[r][1] : -INFINITY;
        float mx = fmaxf(v0, v1);
#pragma unroll
        for (int off = 32; off; off >>= 1) mx = fmaxf(mx, __shfl_xor(mx, off, 64));
        float ss = valid ? (expf(v0 - mx) + expf(v1 - mx)) : 0.0f;
#pragma unroll
        for (int off = 32; off; off >>= 1) ss += __shfl_xor(ss, off, 64);
        float c0 = v0, c1 = v1;
        int i0 = col0, i1 = col0 + 1;
        float tv[4]; int ti[4];
#pragma unroll
        for (int p = 0; p < 4; p++) {
            float bv; int bi;
            if (c0 > c1 || (c0 == c1 && i0 < i1)) { bv = c0; bi = i0; } else { bv = c1; bi = i1; }
#pragma unroll
            for (int off = 32; off; off >>= 1) {
                float ov = __shfl_xor(bv, off, 64);
                int oi = __shfl_xor(bi, off, 64);
                if (ov > bv || (ov == bv && oi < bi)) { bv = ov; bi = oi; }
            }
            if (bi == i0) c0 = -INFINITY;
            else if (bi == i1) c1 = -INFINITY;
            tv[p] = bv; ti[p] = bi;
        }
        if (lane == 0) {
            int m = q * 8 + r;
            int o = m * CHN + bx;
            cst(cmax + o, mx); cst(csum + o, ss);
            cst(ctv + o * 4 + 0, tv[0]); csti(cti + o * 4 + 0, ti[0]);
            cst(ctv + o * 4 + 1, tv[1]); csti(cti + o * 4 + 1, ti[1]);
            cst(ctv + o * 4 + 2, tv[2]); csti(cti + o * 4 + 2, ti[2]);
            cst(ctv + o * 4 + 3, tv[3]); csti(cti + o * 4 + 3, ti[3]);
        }
    }
}

__device__ __forceinline__ void merge_body(float* smem,
                                           const float* __restrict__ cmax,
                                           const float* __restrict__ csum,
                                           const float* __restrict__ ctv,
                                           const int* __restrict__ cti,
                                           float* __restrict__ scores,
                                           int* __restrict__ tokens,
                                           int* __restrict__ beamh,
                                           int* __restrict__ tokh, int t, int b) {
    int tid = threadIdx.x;
    int lane = tid & 63, q = tid >> 6;
    int m = b * 4 + q;
    float* s_old = smem;            // 4
    float* LSE = smem + 4;          // 4
    float* bt_v = smem + 8;         // 16
    int* bt_i = (int*)(smem + 24);  // 16
    if (tid < 4) s_old[tid] = cld(scores + b * 4 + tid);
    float mx = -INFINITY, sm = 0.f;
    for (int c = lane; c < CHN; c += 64) {
        float cm = cld(cmax + m * CHN + c), cs = cld(csum + m * CHN + c);
        if (cm > mx) { sm = sm * expf(mx - cm) + cs; mx = cm; }
        else sm += cs * expf(cm - mx);
    }
#pragma unroll
    for (int off = 32; off; off >>= 1) {
        float om = __shfl_xor(mx, off, 64);
        float os = __shfl_xor(sm, off, 64);
        float M = fmaxf(mx, om);
        sm = sm * expf(mx - M) + os * expf(om - M);
        mx = M;
    }
    if (lane == 0) LSE[q] = mx + logf(sm);
    float lv[4] = {-INFINITY, -INFINITY, -INFINITY, -INFINITY};
    int li[4] = {0x7fffffff, 0x7fffffff, 0x7fffffff, 0x7fffffff};
    for (int c = lane; c < CHN; c += 64) {
        int o = (m * CHN + c) * 4;
#pragma unroll
        for (int j = 0; j < 4; j++) {
            float v = cld(ctv + o + j); int i = cldi(cti + o + j);
            if (v > lv[3] || (v == lv[3] && i < li[3])) {
                lv[3] = v; li[3] = i;
#pragma unroll
                for (int s = 3; s > 0; s--) {
                    if (lv[s] > lv[s - 1] || (lv[s] == lv[s - 1] && li[s] < li[s - 1])) {
                        float tv2 = lv[s]; lv[s] = lv[s - 1]; lv[s - 1] = tv2;
                        int ti2 = li[s]; li[s] = li[s - 1]; li[s - 1] = ti2;
                    }
                }
            }
        }
    }
#pragma unroll
    for (int p = 0; p < 4; p++) {
        float bv = lv[0]; int bi = li[0];
#pragma unroll
        for (int off = 32; off; off >>= 1) {
            float ov = __shfl_xor(bv, off, 64);
            int oi = __shfl_xor(bi, off, 64);
            if (ov > bv || (ov == bv && oi < bi)) { bv = ov; bi = oi; }
        }
        if (li[0] == bi) {
            lv[0] = lv[1]; li[0] = li[1];
            lv[1] = lv[2]; li[1] = li[2];
            lv[2] = lv[3]; li[2] = li[3];
            lv[3] = -INFINITY; li[3] = 0x7fffffff;
        }
        if (lane == 0) { bt_v[q * 4 + p] = bv; bt_i[q * 4 + p] = bi; }
    }
    __syncthreads();
    if (tid == 0) {
        float fv[16]; int fi[16]; bool used[16];
#pragma unroll
        for (int r = 0; r < 4; r++)
#pragma unroll
            for (int p = 0; p < 4; p++) {
                fv[r * 4 + p] = s_old[r] - LSE[r] + bt_v[r * 4 + p];
                fi[r * 4 + p] = r * VOC + bt_i[r * 4 + p];
                used[r * 4 + p] = false;
            }
        for (int kk = 0; kk < 4; kk++) {
            int best = -1;
            for (int c2 = 0; c2 < 16; c2++) {
                if (used[c2]) continue;
                if (best < 0 || fv[c2] > fv[best] || (fv[c2] == fv[best] && fi[c2] < fi[best])) best = c2;
            }
            used[best] = true;
            int beam = fi[best] / VOC;
            int tok = fi[best] - beam * VOC;
            cst(scores + b * 4 + kk, fv[best]);
            csti(tokens + b * 4 + kk, tok);
            csti(beamh + (t * BB + b) * 4 + kk, beam);
            csti(tokh + (t * BB + b) * 4 + kk, tok);
        }
    }
}

__global__ __launch_bounds__(256) void decode_persistent(
    const float* __restrict__ emb, const float* __restrict__ pos,
    const float* __restrict__ Wdq, const float* __restrict__ Wdo,
    const float* __restrict__ Wd1, const float* __restrict__ Wd2,
    const float* __restrict__ Wvoc,
    const float* __restrict__ Kmem, const float* __restrict__ Vmem,
    const float* __restrict__ mb,
    float* __restrict__ x, float* __restrict__ xT,
    float* __restrict__ qdp, float* __restrict__ cctxT, float* __restrict__ cprojp,
    float* __restrict__ hd1, float* __restrict__ hd1T,
    float* __restrict__ dff1p, float* __restrict__ dff2p,
    float* __restrict__ hd2, float* __restrict__ hd2T,
    float* __restrict__ cmax, float* __restrict__ csum,
    float* __restrict__ ctv, int* __restrict__ cti,
    float* __restrict__ scores, int* __restrict__ tokens,
    int* __restrict__ beamh, int* __restrict__ tokh,
    unsigned* abar, unsigned* rbar, float* __restrict__ out) {
    __shared__ float smem[6160];
    int bid = blockIdx.x, tid = threadIdx.x;
    unsigned gen = 0;

    if (bid == 0 && tid < BB * KW) {
        csti(tokens + tid, 101);
        cst(scores + tid, (tid & 3) ? -1e9f : 0.0f);
    }
    gsync(abar, rbar, gen);

    for (int t = 0; t < TT; t++) {
        if (bid < 32) embed_body(smem, tokens, emb, pos, t, x, xT, bid);
        gsync(abar, rbar, gen);
        if (bid < 48) skinny3_body<96, 1, 0, 0>(smem, xT, Wdq, qdp, DMODEL, 0, bid % 6, bid / 6);
        gsync(abar, rbar, gen);
        if (bid < 96) dec_attn_body(smem, qdp, Kmem, Vmem, mb, cctxT, bid);
        gsync(abar, rbar, gen);
        if (bid < 48) skinny3_body<96, 1, 0, 0>(smem, cctxT, Wdo, cprojp, DMODEL, 0, bid % 6, bid / 6);
        gsync(abar, rbar, gen);
        if (bid < 32) lnres_body<8>(smem, x, cprojp, hd1, hd1T, P32C, bid);
        gsync(abar, rbar, gen);
        if (bid < 96) skinny3_body<192, 1, 0, 1>(smem, hd1T, Wd1, dff1p, DFF, 0, bid % 24, bid / 24);
        gsync(abar, rbar, gen);
        if (bid < 48) skinny3_body<384, 4, 1, 0>(smem, dff1p, Wd2, dff2p, DMODEL, DFF * 8, bid % 6, bid / 6);
        gsync(abar, rbar, gen);
        if (bid < 32) lnres_body<8>(smem, hd1, dff2p, hd2, hd2T, P32C, bid);
        gsync(abar, rbar, gen);
        if (bid < CHN) logits_body(smem, hd2T, Wvoc, cmax, csum, ctv, cti, bid);
        gsync(abar, rbar, gen);
        if (bid < BB) merge_body(smem, cmax, csum, ctv, cti, scores, tokens, beamh, tokh, t, bid);
        gsync(abar, rbar, gen);
    }

    if (bid == 0 && tid < BB * KW) {
        int b = tid >> 2, k = tid & 3;
        int ptr = k;
        for (int t = TT - 1; t >= 0; t--) {
            int tok = cldi(tokh + (t * BB + b) * KW + ptr);
            out[(size_t)tid * TT + t] = (float)tok;
            ptr = cldi(beamh + (t * BB + b) * KW + ptr);
        }
        out[BB * KW * TT + tid] = cld(scores + tid);
    }
}

__global__ void init_bar(unsigned* a) {
    a[blockIdx.x * 256 + threadIdx.x] = 0u;
}

extern "C" void kernel_launch(void* const* d_in, const int* in_sizes, int n_in,
                              void* d_out, int out_size, void* d_ws, size_t ws_size,
                              hipStream_t stream) {
    const int* X = (const int*)d_in[0];
    const float* emb = (const float*)d_in[1];
    const float* pos = (const float*)d_in[2];
    const float* Wq = (const float*)d_in[3];
    const float* Wk = (const float*)d_in[4];
    const float* Wv = (const float*)d_in[5];
    const float* Wo = (const float*)d_in[6];
    const float* W1 = (const float*)d_in[7];
    const float* W2 = (const float*)d_in[8];
    const float* Wdq = (const float*)d_in[9];
    const float* Wdk = (const float*)d_in[10];
    const float* Wdv = (const float*)d_in[11];
    const float* Wdo = (const float*)d_in[12];
    const float* Wd1 = (const float*)d_in[13];
    const float* Wd2 = (const float*)d_in[14];
    const float* Wvoc = (const float*)d_in[15];

    float* ws = (float*)d_ws;
    size_t o = 0;
    auto alloc = [&](size_t n) { float* p = ws + o; o += n; return p; };

    const size_t ROWS = (size_t)BB * SS;       // 1024
    const size_t HD = ROWS * DMODEL;
    const size_t P32 = 32 * DMODEL;            // 24576

    // persistent
    float* mb = alloc(ROWS);
    float* Kmem = alloc(HD);
    float* Vmem = alloc(HD);
    float* scores = alloc(32);
    int* tokens = (int*)alloc(32);
    int* beamh = (int*)alloc(TT * BB * KW);
    int* tokh = (int*)alloc(TT * BB * KW);
    unsigned* abar = (unsigned*)alloc(PG * SLOT);
    unsigned* rbar = (unsigned*)alloc(PG * SLOT);

    size_t mark = o;
    // encoder scratch
    float* h0 = alloc(HD);
    float* qb = alloc(HD);
    float* kb = alloc(HD);
    float* vb = alloc(HD);
    float* attc = alloc(HD);
    float* attp = alloc(HD);
    float* h1 = alloc(HD);
    float* ff1 = alloc(ROWS * DFF);
    float* ff2 = alloc(HD);
    float* memb = alloc(HD);

    // decoder scratch (aliases encoder scratch)
    o = mark;
    float* x = alloc(P32);
    float* xT = alloc(P32);
    float* qdp = alloc(8 * P32);
    float* cctxT = alloc(P32);
    float* cprojp = alloc(8 * P32);
    float* hd1 = alloc(P32);
    float* hd1T = alloc(P32);
    float* dff1p = alloc((size_t)4 * DFF * 32);
    float* dff2p = alloc(8 * P32);
    float* hd2 = alloc(P32);
    float* hd2T = alloc(P32);
    float* cmax = alloc(32 * CHN);
    float* csum = alloc(32 * CHN);
    float* ctv = alloc((size_t)32 * CHN * 4);
    int* cti = (int*)alloc((size_t)32 * CHN * 4);
    (void)ws_size; (void)in_sizes; (void)n_in; (void)out_size;

    init_bar<<<dim3((PG * SLOT * 2) / 256), 256, 0, stream>>>(abar);

    // ---- encoder (unchanged) ----
    embed_enc<<<dim3(ROWS), 256, 0, stream>>>(X, emb, pos, h0, mb);
    dim3 g768(DMODEL / 64, ROWS / 64);
    dim3 g3072(DFF / 64, ROWS / 64);
    gemm64<DMODEL, 0><<<g768, 256, 0, stream>>>(h0, Wq, qb, DMODEL);
    gemm64<DMODEL, 0><<<g768, 256, 0, stream>>>(h0, Wk, kb, DMODEL);
    gemm64<DMODEL, 0><<<g768, 256, 0, stream>>>(h0, Wv, vb, DMODEL);
    enc_attn<<<dim3(BB * HN * SS), 64, 0, stream>>>(qb, kb, vb, mb, attc);
    gemm64<DMODEL, 0><<<g768, 256, 0, stream>>>(attc, Wo, attp, DMODEL);
    lnresP<1><<<dim3(ROWS), 256, 0, stream>>>(h0, attp, h1, nullptr, 0, 0);
    gemm64<DMODEL, 1><<<g3072, 256, 0, stream>>>(h1, W1, ff1, DFF);
    gemm64<DFF, 0><<<g768, 256, 0, stream>>>(ff1, W2, ff2, DMODEL);
    lnresP<1><<<dim3(ROWS), 256, 0, stream>>>(h1, ff2, memb, nullptr, 0, 0);
    gemm64<DMODEL, 0><<<g768, 256, 0, stream>>>(memb, Wdk, Kmem, DMODEL);
    gemm64<DMODEL, 0><<<g768, 256, 0, stream>>>(memb, Wdv, Vmem, DMODEL);

    // ---- entire beam-search decode in ONE persistent kernel ----
    decode_persistent<<<dim3(PG), 256, 0, stream>>>(
        emb, pos, Wdq, Wdo, Wd1, Wd2, Wvoc, Kmem, Vmem, mb,
        x, xT, qdp, cctxT, cprojp, hd1, hd1T, dff1p, dff2p, hd2, hd2T,
        cmax, csum, ctv, cti, scores, tokens, beamh, tokh, abar, rbar, (float*)d_out);
}